// Round 9
// baseline (220.806 us; speedup 1.0000x reference)
//
#include <hip/hip_runtime.h>

// BiPointNet fused v9: ONE persistent kernel (ordinary launch, 512 blocks =
// 2 blocks/CU guaranteed co-resident) + software grid barriers (3 counters,
// zeroed per call by k_zero). Each wave owns 4 rows (128 positions) fully in
// registers; only BN stats (16-replica packed u64 atomics) cross blocks.
// Cross-XCD stat reads use agent-scope atomic loads.

typedef unsigned long long u64;
typedef unsigned int u32;

#define P_TOTAL (8192 * 32)
#define NREP 16
#define NBLK 512

__device__ __forceinline__ u64 bcast64(u64 x, int p) {
    unsigned lo = __builtin_amdgcn_readlane((unsigned)x, p);
    unsigned hi = __builtin_amdgcn_readlane((unsigned)(x >> 32), p);
    return ((u64)hi << 32) | lo;
}

__device__ __forceinline__ u64 pack_stats(int sd, int sq) {
    return ((u64)(unsigned)sd << 32) | (u64)(unsigned)sq;
}

// agent-scope atomic accumulate of packed stats
__device__ __forceinline__ void stat_add(u64* p, u64 v) {
    __hip_atomic_fetch_add(p, v, __ATOMIC_RELEASE, __HIP_MEMORY_SCOPE_AGENT);
}

// sum NREP replicas (agent-scope atomic loads: coherent across XCDs),
// fold BN+scale+gamma+beta -> v = a*dot + b
__device__ __forceinline__ void affine_from_stats(u64* st, int c,
        const float* __restrict__ scale, const float* __restrict__ gamma,
        const float* __restrict__ beta, int cparam, float& a, float& b) {
    u64 v = 0;
    #pragma unroll
    for (int r = 0; r < NREP; ++r)
        v += __hip_atomic_load(&st[r * 256 + c], __ATOMIC_RELAXED, __HIP_MEMORY_SCOPE_AGENT);
    int sd = (int)(v >> 32);
    int sq = (int)(unsigned)(v & 0xFFFFFFFFull);
    const double invN = 1.0 / (double)P_TOTAL;
    double m = (double)sd * invN;
    double var = (double)sq * invN - m * m;
    double sc = (double)scale[cparam];
    double inv = 1.0 / sqrt(sc * sc * var + 1e-5);
    double g = (double)gamma[cparam];
    a = (float)(g * inv * sc);
    b = (float)((double)beta[cparam] - g * inv * sc * m);
}

// integer threshold T s.t. fmaf(a,(float)d,b)>0 <=> d' >= T (d'=dot, or -dot if flip)
__device__ __forceinline__ int make_thresh(float a, float b, bool& flip) {
    if (a == 0.f) { flip = false; return (b > 0.f) ? -65 : 65; }
    double r = -(double)b / (double)a;
    r = fmin(fmax(r, -1e6), 1e6);
    int t0 = (int)floor(r);
    int T;
    if (a > 0.f) {
        flip = false;
        T = t0 + 2;
        if (fmaf(a, (float)(t0 + 1), b) > 0.f) T = t0 + 1;
        if (fmaf(a, (float)(t0    ), b) > 0.f) T = t0;
        if (fmaf(a, (float)(t0 - 1), b) > 0.f) T = t0 - 1;
    } else {
        flip = true;
        int H = t0 - 2;
        if (fmaf(a, (float)(t0 - 1), b) > 0.f) H = t0 - 1;
        if (fmaf(a, (float)(t0    ), b) > 0.f) H = t0;
        if (fmaf(a, (float)(t0 + 1), b) > 0.f) H = t0 + 1;
        T = -H;
    }
    return max(-65, min(65, T));
}

// software grid barrier: counter k (zeroed per call), release-inc + acquire-spin
__device__ __forceinline__ void gbar(u32* bar, int k) {
    __syncthreads();
    if (threadIdx.x == 0) {
        __hip_atomic_fetch_add(&bar[k], 1u, __ATOMIC_ACQ_REL, __HIP_MEMORY_SCOPE_AGENT);
        while (__hip_atomic_load(&bar[k], __ATOMIC_ACQUIRE, __HIP_MEMORY_SCOPE_AGENT) < (u32)NBLK)
            __builtin_amdgcn_s_sleep(2);
    }
    __syncthreads();
}

__global__ void k_zero(u64* __restrict__ stats, u32* __restrict__ bar) {
    stats[blockIdx.x * 256 + threadIdx.x] = 0;
    if (blockIdx.x == 0 && threadIdx.x < 16) bar[threadIdx.x] = 0;
}

__global__ void __launch_bounds__(256, 2) kmain(
    const float4* __restrict__ in4,
    const float* __restrict__ W1, const float* __restrict__ s1,
    const float* __restrict__ g1, const float* __restrict__ b1,
    const float* __restrict__ W2, const float* __restrict__ s2,
    const float* __restrict__ g2, const float* __restrict__ b2,
    const float* __restrict__ W3, const float* __restrict__ s3,
    const float* __restrict__ g3, const float* __restrict__ b3,
    float* __restrict__ out, u64* __restrict__ stats, u32* __restrict__ bar) {
    const int lane = threadIdx.x & 63;
    const int wib = threadIdx.x >> 6;
    const int gw = blockIdx.x * 4 + wib;          // 2048 waves; rows 4*gw..4*gw+3
    const int rep = (blockIdx.x & (NREP - 1)) * 256;

    __shared__ int rda[4][64], rqa[4][64], rdb[4][64], rqb[4][64];
    __shared__ int gT[64], gF[64];
    __shared__ float sA[128], sB[128];

    // ---- weight masks: each lane packs its channel-row(s) -----------------
    u64 w1S = 0, w1N = 0, w2P = 0, w2N = 0, w3aP = 0, w3aN = 0, w3bP = 0, w3bN = 0;
    {
        const float4* r1 = (const float4*)(W1 + lane * 64);
        const float4* r2 = (const float4*)(W2 + lane * 64);
        const float4* r3a = (const float4*)(W3 + lane * 64);
        const float4* r3b = (const float4*)(W3 + (lane + 64) * 64);
        #pragma unroll
        for (int j = 0; j < 16; ++j) {
            float4 a = r1[j], b = r2[j], c = r3a[j], d = r3b[j];
            #pragma unroll
            for (int k = 0; k < 4; ++k) {
                const int ch = 4 * j + k;
                const int p1 = ((ch & 3) << 4) | (ch >> 2);   // k1 ballot perm
                float wa = (k == 0) ? a.x : (k == 1) ? a.y : (k == 2) ? a.z : a.w;
                float wb = (k == 0) ? b.x : (k == 1) ? b.y : (k == 2) ? b.z : b.w;
                float wc = (k == 0) ? c.x : (k == 1) ? c.y : (k == 2) ? c.z : c.w;
                float wd = (k == 0) ? d.x : (k == 1) ? d.y : (k == 2) ? d.z : d.w;
                if (wa > 0.f)  w1S |= 1ull << p1;
                if (wa != 0.f) w1N |= 1ull << p1;
                if (wb > 0.f)  w2P |= 1ull << ch;
                if (wb < 0.f)  w2N |= 1ull << ch;
                if (wc > 0.f)  w3aP |= 1ull << ch;
                if (wc < 0.f)  w3aN |= 1ull << ch;
                if (wd > 0.f)  w3bP |= 1ull << ch;
                if (wd < 0.f)  w3bN |= 1ull << ch;
            }
        }
    }

    // ---- phase 1: stream input, pack A1 masks into regs, layer-1 stats ----
    u64 a1s[4], a1n[4];
    {
        int sd = 0, sq = 0;
        #pragma unroll
        for (int un = 0; un < 4; ++un) {
            const size_t base = (size_t)(4 * gw + un) * 512 + lane;
            float4 v0 = in4[base];
            float4 v1 = in4[base + 64];
            float4 v2 = in4[base + 128];
            float4 v3 = in4[base + 192];
            float4 v4 = in4[base + 256];
            float4 v5 = in4[base + 320];
            float4 v6 = in4[base + 384];
            float4 v7 = in4[base + 448];
            u64 ms = 0, mn = 0;
            auto proc = [&](float4 v, int b) {
                u64 bs0 = __ballot(v.x > 0.f), bn0 = __ballot(v.x != 0.f);
                u64 bs1 = __ballot(v.y > 0.f), bn1 = __ballot(v.y != 0.f);
                u64 bs2 = __ballot(v.z > 0.f), bn2 = __ballot(v.z != 0.f);
                u64 bs3 = __ballot(v.w > 0.f), bn3 = __ballot(v.w != 0.f);
                #pragma unroll
                for (int p = 0; p < 4; ++p) {      // wave-uniform slices
                    const int s2 = p << 4;
                    u64 as = ((bs0 >> s2) & 0xFFFFull) | (((bs1 >> s2) & 0xFFFFull) << 16)
                           | (((bs2 >> s2) & 0xFFFFull) << 32) | (((bs3 >> s2) & 0xFFFFull) << 48);
                    u64 an = ((bn0 >> s2) & 0xFFFFull) | (((bn1 >> s2) & 0xFFFFull) << 16)
                           | (((bn2 >> s2) & 0xFFFFull) << 32) | (((bn3 >> s2) & 0xFFFFull) << 48);
                    u64 mnz = an & w1N;
                    int dot = __popcll(mnz) - 2 * __popcll(mnz & (as ^ w1S));
                    sd += dot; sq += dot * dot;
                    if (lane == b * 4 + p) { ms = as; mn = an; }
                }
            };
            proc(v0, 0); proc(v1, 1); proc(v2, 2); proc(v3, 3);
            proc(v4, 4); proc(v5, 5); proc(v6, 6); proc(v7, 7);
            a1s[un] = ms; a1n[un] = mn;
        }
        rda[wib][lane] = sd; rqa[wib][lane] = sq;
        __syncthreads();
        if (threadIdx.x < 64) {
            int td = rda[0][lane] + rda[1][lane] + rda[2][lane] + rda[3][lane];
            int tq = rqa[0][lane] + rqa[1][lane] + rqa[2][lane] + rqa[3][lane];
            stat_add(&stats[rep + lane], pack_stats(td, tq));
            __threadfence();
        }
    }
    gbar(bar, 0);

    // ---- phase 2: layer-1 binarize (int thresh) -> A2 in regs, L2 stats ----
    if (threadIdx.x < 64) {
        float a, b;
        affine_from_stats(stats, threadIdx.x, s1, g1, b1, threadIdx.x, a, b);
        bool fl;
        gT[threadIdx.x] = make_thresh(a, b, fl);
        gF[threadIdx.x] = fl ? 1 : 0;
    }
    __syncthreads();
    u64 a2m[4];
    {
        const int T = gT[lane];
        const u64 w1Sf = gF[lane] ? ~w1S : w1S;    // flip => dot' = -dot
        int sd = 0, sq = 0;
        #pragma unroll
        for (int un = 0; un < 4; ++un) {
            u64 mymask = 0;
            #pragma unroll 8
            for (int p = 0; p < 32; ++p) {
                u64 as = bcast64(a1s[un], p);
                u64 an = bcast64(a1n[un], p);
                u64 mnz = an & w1N;
                int dot1 = __popcll(mnz) - 2 * __popcll(mnz & (as ^ w1Sf));
                u64 A = __ballot(dot1 >= T);
                if (lane == p) mymask = A;
                int d2 = __popcll(A & w2P) - __popcll(A & w2N);
                sd += d2; sq += d2 * d2;
            }
            a2m[un] = mymask;
        }
        __syncthreads();
        rda[wib][lane] = sd; rqa[wib][lane] = sq;
        __syncthreads();
        if (threadIdx.x < 64) {
            int td = rda[0][lane] + rda[1][lane] + rda[2][lane] + rda[3][lane];
            int tq = rqa[0][lane] + rqa[1][lane] + rqa[2][lane] + rqa[3][lane];
            stat_add(&stats[rep + 64 + lane], pack_stats(td, tq));
            __threadfence();
        }
    }
    gbar(bar, 1);

    // ---- phase 3: layer-2 binarize, layer-3 dots -> stats + row max/min ----
    if (threadIdx.x < 64) {
        float a, b;
        affine_from_stats(stats, 64 + threadIdx.x, s2, g2, b2, threadIdx.x, a, b);
        bool fl;
        gT[threadIdx.x] = make_thresh(a, b, fl);
        gF[threadIdx.x] = fl ? 1 : 0;
    }
    __syncthreads();
    int mxa[4], mna[4], mxb[4], mnb[4];
    {
        const int T = gT[lane];
        const u64 w2Pf = gF[lane] ? w2N : w2P;     // flip => swap pos/neg
        const u64 w2Nf = gF[lane] ? w2P : w2N;
        int sda = 0, sqa = 0, sdb = 0, sqb = 0;
        #pragma unroll
        for (int un = 0; un < 4; ++un) {
            int xa = -127, na = 127, xb = -127, nb = 127;
            #pragma unroll 8
            for (int p = 0; p < 32; ++p) {
                u64 A = bcast64(a2m[un], p);
                int d2 = __popcll(A & w2Pf) - __popcll(A & w2Nf);
                u64 A3 = __ballot(d2 >= T);
                int da = __popcll(A3 & w3aP) - __popcll(A3 & w3aN);
                int db = __popcll(A3 & w3bP) - __popcll(A3 & w3bN);
                sda += da; sqa += da * da; sdb += db; sqb += db * db;
                xa = max(xa, da); na = min(na, da);
                xb = max(xb, db); nb = min(nb, db);
            }
            mxa[un] = xa; mna[un] = na; mxb[un] = xb; mnb[un] = nb;
        }
        __syncthreads();
        rda[wib][lane] = sda; rqa[wib][lane] = sqa;
        rdb[wib][lane] = sdb; rqb[wib][lane] = sqb;
        __syncthreads();
        if (threadIdx.x < 64) {
            int tda = rda[0][lane] + rda[1][lane] + rda[2][lane] + rda[3][lane];
            int tqa = rqa[0][lane] + rqa[1][lane] + rqa[2][lane] + rqa[3][lane];
            int tdb = rdb[0][lane] + rdb[1][lane] + rdb[2][lane] + rdb[3][lane];
            int tqb = rqb[0][lane] + rqb[1][lane] + rqb[2][lane] + rqb[3][lane];
            stat_add(&stats[rep + 128 + lane], pack_stats(tda, tqa));
            stat_add(&stats[rep + 192 + lane], pack_stats(tdb, tqb));
            __threadfence();
        }
    }
    gbar(bar, 2);

    // ---- phase 4: v = a*(a>=0?dmax:dmin)+b, ReLU, write [8192,128] ---------
    if (threadIdx.x < 128) {
        affine_from_stats(stats, 128 + threadIdx.x, s3, g3, b3, threadIdx.x,
                          sA[threadIdx.x], sB[threadIdx.x]);
    }
    __syncthreads();
    {
        const float aa = sA[lane], ba = sB[lane];
        const float ab = sA[64 + lane], bb = sB[64 + lane];
        #pragma unroll
        for (int un = 0; un < 4; ++un) {
            const int m = 4 * gw + un;
            float va = fmaf(aa, (float)(aa >= 0.f ? mxa[un] : mna[un]), ba);
            float vb = fmaf(ab, (float)(ab >= 0.f ? mxb[un] : mnb[un]), bb);
            out[(size_t)m * 128 + lane] = fmaxf(va, 0.f);
            out[(size_t)m * 128 + 64 + lane] = fmaxf(vb, 0.f);
        }
    }
}

extern "C" void kernel_launch(void* const* d_in, const int* in_sizes, int n_in,
                              void* d_out, int out_size, void* d_ws, size_t ws_size,
                              hipStream_t stream) {
    const float4* in4 = (const float4*)d_in[0];
    const float* W1 = (const float*)d_in[1];
    const float* s1 = (const float*)d_in[2];
    const float* g1 = (const float*)d_in[3];
    const float* b1 = (const float*)d_in[4];
    const float* W2 = (const float*)d_in[5];
    const float* s2 = (const float*)d_in[6];
    const float* g2 = (const float*)d_in[7];
    const float* b2 = (const float*)d_in[8];
    const float* W3 = (const float*)d_in[9];
    const float* s3 = (const float*)d_in[10];
    const float* g3 = (const float*)d_in[11];
    const float* b3 = (const float*)d_in[12];
    float* out = (float*)d_out;
    u64* stats = (u64*)d_ws;                       // 16 reps x 256 u64 = 32 KB
    u32* bar = (u32*)((char*)d_ws + 32768);        // 3 barrier counters

    k_zero<<<16, 256, 0, stream>>>(stats, bar);
    kmain<<<NBLK, 256, 0, stream>>>(in4, W1, s1, g1, b1, W2, s2, g2, b2,
                                    W3, s3, g3, b3, out, stats, bar);
}

// Round 10
// 130.676 us; speedup vs baseline: 1.6897x; 1.6897x over previous
//
#include <hip/hip_runtime.h>

// BiPointNet fused v10: ONE persistent kernel, 1024-thread blocks (16 waves),
// grid = occupancy-derived blocks/CU * 256 (co-residency by construction),
// software grid barriers + agent-scope packed BN-stat atomics (R9-proven).
// 16 waves/CU = 4 waves/SIMD, the measured saturation point of the phase
// bodies (R6->R7). Weight masks packed per-block into LDS. 2 launches total.

typedef unsigned long long u64;
typedef unsigned int u32;

#define P_TOTAL (8192 * 32)
#define NREP 16

__device__ __forceinline__ u64 bcast64(u64 x, int p) {
    unsigned lo = __builtin_amdgcn_readlane((unsigned)x, p);
    unsigned hi = __builtin_amdgcn_readlane((unsigned)(x >> 32), p);
    return ((u64)hi << 32) | lo;
}

__device__ __forceinline__ u64 pack_stats(int sd, int sq) {
    return ((u64)(unsigned)sd << 32) | (u64)(unsigned)sq;
}

__device__ __forceinline__ void stat_add(u64* p, u64 v) {
    __hip_atomic_fetch_add(p, v, __ATOMIC_RELEASE, __HIP_MEMORY_SCOPE_AGENT);
}

// sum NREP replicas (agent-scope loads), fold BN+scale+gamma+beta -> a*dot+b
__device__ __forceinline__ void affine_from_stats(u64* st, int c,
        const float* __restrict__ scale, const float* __restrict__ gamma,
        const float* __restrict__ beta, int cparam, float& a, float& b) {
    u64 v = 0;
    #pragma unroll
    for (int r = 0; r < NREP; ++r)
        v += __hip_atomic_load(&st[r * 256 + c], __ATOMIC_RELAXED, __HIP_MEMORY_SCOPE_AGENT);
    int sd = (int)(v >> 32);
    int sq = (int)(unsigned)(v & 0xFFFFFFFFull);
    const double invN = 1.0 / (double)P_TOTAL;
    double m = (double)sd * invN;
    double var = (double)sq * invN - m * m;
    double sc = (double)scale[cparam];
    double inv = 1.0 / sqrt(sc * sc * var + 1e-5);
    double g = (double)gamma[cparam];
    a = (float)(g * inv * sc);
    b = (float)((double)beta[cparam] - g * inv * sc * m);
}

// integer threshold T s.t. fmaf(a,(float)d,b)>0 <=> d' >= T (d'=dot; -dot if flip)
__device__ __forceinline__ int make_thresh(float a, float b, bool& flip) {
    if (a == 0.f) { flip = false; return (b > 0.f) ? -65 : 65; }
    double r = -(double)b / (double)a;
    r = fmin(fmax(r, -1e6), 1e6);
    int t0 = (int)floor(r);
    int T;
    if (a > 0.f) {
        flip = false;
        T = t0 + 2;
        if (fmaf(a, (float)(t0 + 1), b) > 0.f) T = t0 + 1;
        if (fmaf(a, (float)(t0    ), b) > 0.f) T = t0;
        if (fmaf(a, (float)(t0 - 1), b) > 0.f) T = t0 - 1;
    } else {
        flip = true;
        int H = t0 - 2;
        if (fmaf(a, (float)(t0 - 1), b) > 0.f) H = t0 - 1;
        if (fmaf(a, (float)(t0    ), b) > 0.f) H = t0;
        if (fmaf(a, (float)(t0 + 1), b) > 0.f) H = t0 + 1;
        T = -H;
    }
    return max(-65, min(65, T));
}

// software grid barrier (counters zeroed per call by k_zero)
__device__ __forceinline__ void gbar(u32* bar, int k, u32 nblk) {
    __syncthreads();
    if (threadIdx.x == 0) {
        __hip_atomic_fetch_add(&bar[k], 1u, __ATOMIC_ACQ_REL, __HIP_MEMORY_SCOPE_AGENT);
        while (__hip_atomic_load(&bar[k], __ATOMIC_ACQUIRE, __HIP_MEMORY_SCOPE_AGENT) < nblk)
            __builtin_amdgcn_s_sleep(2);
    }
    __syncthreads();
}

__global__ void k_zero(u64* __restrict__ stats, u32* __restrict__ bar) {
    stats[blockIdx.x * 256 + threadIdx.x] = 0;
    if (blockIdx.x == 0 && threadIdx.x < 16) bar[threadIdx.x] = 0;
}

__global__ void __launch_bounds__(1024, 4) kfused(
    const float4* __restrict__ in4,
    const float* __restrict__ W1, const float* __restrict__ s1,
    const float* __restrict__ g1, const float* __restrict__ b1,
    const float* __restrict__ W2, const float* __restrict__ s2,
    const float* __restrict__ g2, const float* __restrict__ b2,
    const float* __restrict__ W3, const float* __restrict__ s3,
    const float* __restrict__ g3, const float* __restrict__ b3,
    float* __restrict__ out, u64* __restrict__ stats, u32* __restrict__ bar) {
    const int lane = threadIdx.x & 63;
    const int wib = threadIdx.x >> 6;              // 0..15
    const u32 nblk = gridDim.x;
    const int TOTW = (int)nblk << 4;
    const int gw = ((int)blockIdx.x << 4) | wib;
    const int rep = (blockIdx.x & (NREP - 1)) * 256;
    const int r0 = gw, r1 = gw + TOTW;
    const bool h0 = r0 < 8192, h1 = r1 < 8192;

    __shared__ u64 wlds[512];                      // 4 KB weight masks
    __shared__ int redA[16][64], redB[16][64], redC[16][64], redD[16][64]; // 16 KB
    __shared__ int gT[64], gF[64];
    __shared__ float sA[128], sB[128];

    // ---- pack weight masks into LDS (threads 0..255, one row each) --------
    if (threadIdx.x < 256) {
        const int t = threadIdx.x;
        const float* src; int dstoff; bool perm, l1m;
        if (t < 64)       { src = W1 + t * 64;         dstoff = 2 * t;              perm = true;  l1m = true;  }
        else if (t < 128) { src = W2 + (t - 64) * 64;  dstoff = 128 + 2 * (t - 64); perm = false; l1m = false; }
        else              { src = W3 + (t - 128) * 64; dstoff = 256 + 2 * (t - 128); perm = false; l1m = false; }
        const float4* s4 = (const float4*)src;
        u64 hiM = 0, loM = 0;
        #pragma unroll
        for (int j = 0; j < 16; ++j) {
            float4 v = s4[j];
            #pragma unroll
            for (int k = 0; k < 4; ++k) {
                const float w = (k == 0) ? v.x : (k == 1) ? v.y : (k == 2) ? v.z : v.w;
                const int c = 4 * j + k;
                const int p = perm ? (((c & 3) << 4) | (c >> 2)) : c;   // k1 ballot perm
                const bool bh = (w > 0.f);
                const bool bl = l1m ? (w != 0.f) : (w < 0.f);
                if (bh) hiM |= 1ull << p;
                if (bl) loM |= 1ull << p;
            }
        }
        wlds[dstoff] = hiM; wlds[dstoff + 1] = loM;
    }
    __syncthreads();

    // per-lane weight registers (lane = channel)
    const u64 w1S = wlds[2 * lane],        w1N = wlds[2 * lane + 1];        // sign,nz
    const u64 w2P = wlds[128 + 2 * lane],  w2N = wlds[129 + 2 * lane];      // pos,neg
    const u64 w3aP = wlds[256 + 2 * lane], w3aN = wlds[257 + 2 * lane];
    const u64 w3bP = wlds[256 + 2 * (lane + 64)], w3bN = wlds[257 + 2 * (lane + 64)];

    // ---- phase 1: stream input, pack A1 masks (regs), layer-1 stats -------
    u64 a1s0 = 0, a1n0 = 0, a1s1 = 0, a1n1 = 0;
    {
        int sd = 0, sq = 0;
        auto ph1row = [&](int r, u64& ms, u64& mn) {
            const size_t base = (size_t)r * 512 + lane;
            float4 v0 = in4[base];
            float4 v1 = in4[base + 64];
            float4 v2 = in4[base + 128];
            float4 v3 = in4[base + 192];
            float4 v4 = in4[base + 256];
            float4 v5 = in4[base + 320];
            float4 v6 = in4[base + 384];
            float4 v7 = in4[base + 448];
            auto proc = [&](float4 v, int b) {
                u64 bs0 = __ballot(v.x > 0.f), bn0 = __ballot(v.x != 0.f);
                u64 bs1 = __ballot(v.y > 0.f), bn1 = __ballot(v.y != 0.f);
                u64 bs2 = __ballot(v.z > 0.f), bn2 = __ballot(v.z != 0.f);
                u64 bs3 = __ballot(v.w > 0.f), bn3 = __ballot(v.w != 0.f);
                #pragma unroll
                for (int p = 0; p < 4; ++p) {      // wave-uniform slices
                    const int s2 = p << 4;
                    u64 as = ((bs0 >> s2) & 0xFFFFull) | (((bs1 >> s2) & 0xFFFFull) << 16)
                           | (((bs2 >> s2) & 0xFFFFull) << 32) | (((bs3 >> s2) & 0xFFFFull) << 48);
                    u64 an = ((bn0 >> s2) & 0xFFFFull) | (((bn1 >> s2) & 0xFFFFull) << 16)
                           | (((bn2 >> s2) & 0xFFFFull) << 32) | (((bn3 >> s2) & 0xFFFFull) << 48);
                    u64 mnz = an & w1N;
                    int dot = __popcll(mnz) - 2 * __popcll(mnz & (as ^ w1S));
                    sd += dot; sq += dot * dot;
                    if (lane == b * 4 + p) { ms = as; mn = an; }   // my position
                }
            };
            proc(v0, 0); proc(v1, 1); proc(v2, 2); proc(v3, 3);
            proc(v4, 4); proc(v5, 5); proc(v6, 6); proc(v7, 7);
        };
        if (h0) ph1row(r0, a1s0, a1n0);
        if (h1) ph1row(r1, a1s1, a1n1);
        redA[wib][lane] = sd; redB[wib][lane] = sq;
        __syncthreads();
        if (threadIdx.x < 64) {
            int td = 0, tq = 0;
            #pragma unroll
            for (int w = 0; w < 16; ++w) { td += redA[w][lane]; tq += redB[w][lane]; }
            stat_add(&stats[rep + lane], pack_stats(td, tq));
            __threadfence();
        }
    }
    gbar(bar, 0, nblk);

    // ---- phase 2: layer-1 binarize (int thresh) -> A2 regs, L2 stats ------
    if (threadIdx.x < 64) {
        float a, b;
        affine_from_stats(stats, threadIdx.x, s1, g1, b1, threadIdx.x, a, b);
        bool fl;
        gT[threadIdx.x] = make_thresh(a, b, fl);
        gF[threadIdx.x] = fl ? 1 : 0;
    }
    __syncthreads();
    u64 a2m0 = 0, a2m1 = 0;
    {
        const int T = gT[lane];
        const u64 w1Sf = gF[lane] ? ~w1S : w1S;    // flip => dot' = -dot
        int sd = 0, sq = 0;
        auto ph2row = [&](u64 as_r, u64 an_r, u64& a2out) {
            u64 mymask = 0;
            #pragma unroll 8
            for (int p = 0; p < 32; ++p) {
                u64 as = bcast64(as_r, p);
                u64 an = bcast64(an_r, p);
                u64 mnz = an & w1N;
                int dot1 = __popcll(mnz) - 2 * __popcll(mnz & (as ^ w1Sf));
                u64 A = __ballot(dot1 >= T);
                if (lane == p) mymask = A;
                int d2 = __popcll(A & w2P) - __popcll(A & w2N);
                sd += d2; sq += d2 * d2;
            }
            a2out = mymask;
        };
        if (h0) ph2row(a1s0, a1n0, a2m0);
        if (h1) ph2row(a1s1, a1n1, a2m1);
        __syncthreads();
        redA[wib][lane] = sd; redB[wib][lane] = sq;
        __syncthreads();
        if (threadIdx.x < 64) {
            int td = 0, tq = 0;
            #pragma unroll
            for (int w = 0; w < 16; ++w) { td += redA[w][lane]; tq += redB[w][lane]; }
            stat_add(&stats[rep + 64 + lane], pack_stats(td, tq));
            __threadfence();
        }
    }
    gbar(bar, 1, nblk);

    // ---- phase 3: layer-2 binarize, layer-3 dots -> stats + row max/min ---
    if (threadIdx.x < 64) {
        float a, b;
        affine_from_stats(stats, 64 + threadIdx.x, s2, g2, b2, threadIdx.x, a, b);
        bool fl;
        gT[threadIdx.x] = make_thresh(a, b, fl);
        gF[threadIdx.x] = fl ? 1 : 0;
    }
    __syncthreads();
    int mxa0 = -127, mna0 = 127, mxb0 = -127, mnb0 = 127;
    int mxa1 = -127, mna1 = 127, mxb1 = -127, mnb1 = 127;
    {
        const int T = gT[lane];
        const u64 w2Pf = gF[lane] ? w2N : w2P;     // flip => swap pos/neg
        const u64 w2Nf = gF[lane] ? w2P : w2N;
        int sda = 0, sqa = 0, sdb = 0, sqb = 0;
        auto ph3row = [&](u64 a2row, int& xa, int& na, int& xb, int& nb) {
            #pragma unroll 8
            for (int p = 0; p < 32; ++p) {
                u64 A = bcast64(a2row, p);
                int d2 = __popcll(A & w2Pf) - __popcll(A & w2Nf);
                u64 A3 = __ballot(d2 >= T);
                int da = __popcll(A3 & w3aP) - __popcll(A3 & w3aN);
                int db = __popcll(A3 & w3bP) - __popcll(A3 & w3bN);
                sda += da; sqa += da * da; sdb += db; sqb += db * db;
                xa = max(xa, da); na = min(na, da);
                xb = max(xb, db); nb = min(nb, db);
            }
        };
        if (h0) ph3row(a2m0, mxa0, mna0, mxb0, mnb0);
        if (h1) ph3row(a2m1, mxa1, mna1, mxb1, mnb1);
        __syncthreads();
        redA[wib][lane] = sda; redB[wib][lane] = sqa;
        redC[wib][lane] = sdb; redD[wib][lane] = sqb;
        __syncthreads();
        if (threadIdx.x < 64) {
            int tda = 0, tqa = 0, tdb = 0, tqb = 0;
            #pragma unroll
            for (int w = 0; w < 16; ++w) {
                tda += redA[w][lane]; tqa += redB[w][lane];
                tdb += redC[w][lane]; tqb += redD[w][lane];
            }
            stat_add(&stats[rep + 128 + lane], pack_stats(tda, tqa));
            stat_add(&stats[rep + 192 + lane], pack_stats(tdb, tqb));
            __threadfence();
        }
    }
    gbar(bar, 2, nblk);

    // ---- phase 4: v = a*(a>=0?dmax:dmin)+b, ReLU, write [8192,128] --------
    if (threadIdx.x < 128) {
        affine_from_stats(stats, 128 + threadIdx.x, s3, g3, b3, threadIdx.x,
                          sA[threadIdx.x], sB[threadIdx.x]);
    }
    __syncthreads();
    {
        const float aa = sA[lane], ba = sB[lane];
        const float ab = sA[64 + lane], bb = sB[64 + lane];
        if (h0) {
            float va = fmaf(aa, (float)(aa >= 0.f ? mxa0 : mna0), ba);
            float vb = fmaf(ab, (float)(ab >= 0.f ? mxb0 : mnb0), bb);
            out[(size_t)r0 * 128 + lane] = fmaxf(va, 0.f);
            out[(size_t)r0 * 128 + 64 + lane] = fmaxf(vb, 0.f);
        }
        if (h1) {
            float va = fmaf(aa, (float)(aa >= 0.f ? mxa1 : mna1), ba);
            float vb = fmaf(ab, (float)(ab >= 0.f ? mxb1 : mnb1), bb);
            out[(size_t)r1 * 128 + lane] = fmaxf(va, 0.f);
            out[(size_t)r1 * 128 + 64 + lane] = fmaxf(vb, 0.f);
        }
    }
}

extern "C" void kernel_launch(void* const* d_in, const int* in_sizes, int n_in,
                              void* d_out, int out_size, void* d_ws, size_t ws_size,
                              hipStream_t stream) {
    const float4* in4 = (const float4*)d_in[0];
    const float* W1 = (const float*)d_in[1];
    const float* s1 = (const float*)d_in[2];
    const float* g1 = (const float*)d_in[3];
    const float* b1 = (const float*)d_in[4];
    const float* W2 = (const float*)d_in[5];
    const float* s2 = (const float*)d_in[6];
    const float* g2 = (const float*)d_in[7];
    const float* b2 = (const float*)d_in[8];
    const float* W3 = (const float*)d_in[9];
    const float* s3 = (const float*)d_in[10];
    const float* g3 = (const float*)d_in[11];
    const float* b3 = (const float*)d_in[12];
    float* out = (float*)d_out;
    u64* stats = (u64*)d_ws;                       // 16 reps x 256 u64 = 32 KB
    u32* bar = (u32*)((char*)d_ws + 32768);        // barrier counters

    // co-residency by construction: blocks = (blocks/CU from occupancy) * 256
    int occ = 1;
    (void)hipOccupancyMaxActiveBlocksPerMultiprocessor(&occ, (const void*)kfused, 1024, 0);
    if (occ < 1) occ = 1;
    int nblk = occ * 256;
    if (nblk > 512) nblk = 512;                    // 8192 waves = 1 row each; more is idle

    k_zero<<<16, 256, 0, stream>>>(stats, bar);
    kfused<<<nblk, 1024, 0, stream>>>(in4, W1, s1, g1, b1, W2, s2, g2, b2,
                                      W3, s3, g3, b3, out, stats, bar);
}

// Round 12
// 94.192 us; speedup vs baseline: 2.3442x; 1.3873x over previous
//
#include <hip/hip_runtime.h>

// BiPointNet v12: v11 (i8 MFMA popcount-GEMM replacement) with the writelane
// builtin replaced by a wave-uniform select (ballot result is uniform, so
// lane picks its own word: 2 VALU per pair). Structure: kA f32->sign-i8 A1
// (16MB) + stats1; kC A1 -MFMA-> D1 -> int-thresh binarize -> A2 ballots
// (2MB) -MFMA-> D2 stats2; kD A2 -> D2 -> binarize -> A3 -MFMA-> D3 stats3
// + row max/min; kE epilogue.

typedef unsigned long long u64;
typedef unsigned int u32;
typedef int v4i __attribute__((ext_vector_type(4)));

#define P_TOTAL (8192 * 32)
#define NREP 16

__device__ __forceinline__ u64 pack_stats(int sd, int sq) {
    return ((u64)(unsigned)sd << 32) | (u64)(unsigned)sq;
}

__device__ __forceinline__ v4i mfma_i8(v4i a, v4i b, v4i c) {
    return __builtin_amdgcn_mfma_i32_16x16x64_i8(a, b, c, 0, 0, 0);
}

// ternary i8 B-fragment of W (row-major [out][64]) for out-channel group g:
// col = lane&15 (out ch within group), k = (lane>>4)*16 + j (in ch)
__device__ __forceinline__ v4i pack_wfrag(const float* __restrict__ W, int g, int lane) {
    const float* p = W + (g * 16 + (lane & 15)) * 64 + (lane >> 4) * 16;
    v4i r;
    #pragma unroll
    for (int d = 0; d < 4; ++d) {
        u32 w = 0;
        #pragma unroll
        for (int b = 0; b < 4; ++b) {
            float x = p[d * 4 + b];
            u32 s = (x > 0.f) ? 1u : ((x < 0.f) ? 0xFFu : 0u);
            w |= s << (8 * b);
        }
        r[d] = (int)w;
    }
    return r;
}

// sum NREP replicas, fold BN+scale+gamma+beta -> v = a*dot + b
__device__ __forceinline__ void affine_from_stats(const u64* __restrict__ st,
        int c, const float* __restrict__ scale, const float* __restrict__ gamma,
        const float* __restrict__ beta, int cparam, float& a, float& b) {
    u64 v = 0;
    #pragma unroll
    for (int r = 0; r < NREP; ++r) v += st[r * 256 + c];
    int sd = (int)(v >> 32);
    int sq = (int)(unsigned)(v & 0xFFFFFFFFull);
    const double invN = 1.0 / (double)P_TOTAL;
    double m = (double)sd * invN;
    double var = (double)sq * invN - m * m;
    double sc = (double)scale[cparam];
    double inv = 1.0 / sqrt(sc * sc * var + 1e-5);
    double g = (double)gamma[cparam];
    a = (float)(g * inv * sc);
    b = (float)((double)beta[cparam] - g * inv * sc * m);
}

// integer threshold: fmaf(a,(float)d,b)>0 <=> (flip? -d : d) >= T. Exact.
__device__ __forceinline__ int make_thresh(float a, float b, bool& flip) {
    if (a == 0.f) { flip = false; return (b > 0.f) ? -65 : 65; }
    double r = -(double)b / (double)a;
    r = fmin(fmax(r, -1e6), 1e6);
    int t0 = (int)floor(r);
    int T;
    if (a > 0.f) {
        flip = false;
        T = t0 + 2;
        if (fmaf(a, (float)(t0 + 1), b) > 0.f) T = t0 + 1;
        if (fmaf(a, (float)(t0    ), b) > 0.f) T = t0;
        if (fmaf(a, (float)(t0 - 1), b) > 0.f) T = t0 - 1;
    } else {
        flip = true;
        int H = t0 - 2;
        if (fmaf(a, (float)(t0 - 1), b) > 0.f) H = t0 - 1;
        if (fmaf(a, (float)(t0    ), b) > 0.f) H = t0;
        if (fmaf(a, (float)(t0 + 1), b) > 0.f) H = t0 + 1;
        T = -H;
    }
    return max(-65, min(65, T));
}

// bit->byte LUT ({0,1} bytes), built per block
__device__ __forceinline__ void build_lut(u64* lut) {
    if (threadIdx.x < 256) {
        int t = threadIdx.x;
        u64 e = 0;
        #pragma unroll
        for (int i = 0; i < 8; ++i) e |= (u64)((t >> i) & 1) << (8 * i);
        lut[t] = e;
    }
}

// expand this lane's A-fragment from ballot words vst (lane 2i: lo of m(i))
__device__ __forceinline__ v4i frag_from_vst(u32 vst, const u64* lut, int lane) {
    int src = 8 * (((lane >> 4) << 2) | (lane & 3));
    u32 lo = (u32)__builtin_amdgcn_ds_bpermute(src, (int)vst);
    u32 hi = (u32)__builtin_amdgcn_ds_bpermute(src + 4, (int)vst);
    u64 bits = ((u64)hi << 32) | lo;
    u32 b16 = (u32)(bits >> ((((lane & 15) >> 2)) * 16)) & 0xFFFFu;
    u64 e0 = lut[b16 & 0xFF], e1 = lut[b16 >> 8];
    v4i a;
    a[0] = (int)(u32)e0; a[1] = (int)(u32)(e0 >> 32);
    a[2] = (int)(u32)e1; a[3] = (int)(u32)(e1 >> 32);
    return a;
}

__device__ __forceinline__ v4i frag_from_bits(u64 bits, const u64* lut, int lane) {
    u32 b16 = (u32)(bits >> ((((lane & 15) >> 2)) * 16)) & 0xFFFFu;
    u64 e0 = lut[b16 & 0xFF], e1 = lut[b16 >> 8];
    v4i a;
    a[0] = (int)(u32)e0; a[1] = (int)(u32)(e0 >> 32);
    a[2] = (int)(u32)e1; a[3] = (int)(u32)(e1 >> 32);
    return a;
}

// wave-uniform mask m for pair pi -> lanes 2pi/2pi+1 capture lo/hi words
__device__ __forceinline__ u32 vst_select(u32 vst, u64 m, int pi, int lane) {
    u32 sel = (lane & 1) ? (u32)(m >> 32) : (u32)m;
    return ((lane >> 1) == pi) ? sel : vst;
}

// ---------------- K0: W1 masks (for kA stats) + zero stats ------------------
__global__ void k0_pack(const float* __restrict__ W1, ulonglong2* __restrict__ wp1,
                        u64* __restrict__ stats) {
    const int t = threadIdx.x;
    #pragma unroll
    for (int r = 0; r < NREP; ++r) stats[r * 256 + t] = 0;
    if (t < 64) {
        const float4* s4 = (const float4*)(W1 + t * 64);
        u64 s = 0, nz = 0;
        #pragma unroll
        for (int j = 0; j < 16; ++j) {
            float4 v = s4[j];
            #pragma unroll
            for (int k = 0; k < 4; ++k) {
                const float w = (k == 0) ? v.x : (k == 1) ? v.y : (k == 2) ? v.z : v.w;
                const int c = 4 * j + k;
                const int p = ((c & 3) << 4) | (c >> 2);   // ballot perm
                if (w > 0.f) s |= 1ull << p;
                if (w != 0.f) nz |= 1ull << p;
            }
        }
        wp1[t] = make_ulonglong2(s, nz);
    }
}

// ------- kA: input -> sign-i8 A1 (16MB) + layer-1 stats (ballot path) -------
__global__ void __launch_bounds__(256) kA(
    const float4* __restrict__ in4, const ulonglong2* __restrict__ wp1,
    u32* __restrict__ A1u, u64* __restrict__ stats) {
    const int lane = threadIdx.x & 63;
    const int wib = threadIdx.x >> 6;
    const int wid = (blockIdx.x << 2) | wib;       // 8192 waves x 32 positions
    const ulonglong2 w = wp1[lane];
    const size_t base = (size_t)wid * 512 + lane;

    float4 v0 = in4[base];
    float4 v1 = in4[base + 64];
    float4 v2 = in4[base + 128];
    float4 v3 = in4[base + 192];
    float4 v4 = in4[base + 256];
    float4 v5 = in4[base + 320];
    float4 v6 = in4[base + 384];
    float4 v7 = in4[base + 448];

    int sd = 0, sq = 0;
    auto sgn = [](float x) -> u32 { return x > 0.f ? 1u : (x < 0.f ? 0xFFu : 0u); };
    auto proc = [&](float4 v, int j) {
        u32 pk = sgn(v.x) | (sgn(v.y) << 8) | (sgn(v.z) << 16) | (sgn(v.w) << 24);
        A1u[base + (size_t)j * 64] = pk;
        u64 bs0 = __ballot(v.x > 0.f), bn0 = __ballot(v.x != 0.f);
        u64 bs1 = __ballot(v.y > 0.f), bn1 = __ballot(v.y != 0.f);
        u64 bs2 = __ballot(v.z > 0.f), bn2 = __ballot(v.z != 0.f);
        u64 bs3 = __ballot(v.w > 0.f), bn3 = __ballot(v.w != 0.f);
        #pragma unroll
        for (int p = 0; p < 4; ++p) {
            const int s2 = p << 4;
            u64 as = ((bs0 >> s2) & 0xFFFFull) | (((bs1 >> s2) & 0xFFFFull) << 16)
                   | (((bs2 >> s2) & 0xFFFFull) << 32) | (((bs3 >> s2) & 0xFFFFull) << 48);
            u64 an = ((bn0 >> s2) & 0xFFFFull) | (((bn1 >> s2) & 0xFFFFull) << 16)
                   | (((bn2 >> s2) & 0xFFFFull) << 32) | (((bn3 >> s2) & 0xFFFFull) << 48);
            u64 mnz = an & w.y;
            int dot = __popcll(mnz) - 2 * __popcll(mnz & (as ^ w.x));
            sd += dot; sq += dot * dot;
        }
    };
    proc(v0, 0); proc(v1, 1); proc(v2, 2); proc(v3, 3);
    proc(v4, 4); proc(v5, 5); proc(v6, 6); proc(v7, 7);

    __shared__ int rd[4][64], rq[4][64];
    rd[wib][lane] = sd; rq[wib][lane] = sq;
    __syncthreads();
    if (threadIdx.x < 64) {
        int td = rd[0][lane] + rd[1][lane] + rd[2][lane] + rd[3][lane];
        int tq = rq[0][lane] + rq[1][lane] + rq[2][lane] + rq[3][lane];
        atomicAdd(&stats[(blockIdx.x & (NREP - 1)) * 256 + lane], pack_stats(td, tq));
    }
}

// -- kC: A1 i8 -> MFMA D1 -> binarize -> A2 ballots; MFMA D2 -> stats2 -------
__global__ void __launch_bounds__(256) kC(
    const v4i* __restrict__ A1f, const float* __restrict__ W1,
    const float* __restrict__ W2, const float* __restrict__ s1,
    const float* __restrict__ g1, const float* __restrict__ b1,
    u32* __restrict__ A2B, u64* __restrict__ stats) {
    __shared__ u64 lut[256];
    __shared__ int Tl[64], Fl[64];
    __shared__ u64 red[4][4][64];
    build_lut(lut);
    if (threadIdx.x < 64) {
        float a, b;
        affine_from_stats(stats, threadIdx.x, s1, g1, b1, threadIdx.x, a, b);
        bool fl;
        Tl[threadIdx.x] = make_thresh(a, b, fl);
        Fl[threadIdx.x] = fl ? 1 : 0;
    }
    __syncthreads();

    const int lane = threadIdx.x & 63;
    const int wib = threadIdx.x >> 6;
    const int wg = (blockIdx.x << 2) | wib;        // 4096 waves x 4 tiles(64 pos)

    v4i B1[4], B2[4];
    int T1[4], F1[4];
    #pragma unroll
    for (int g = 0; g < 4; ++g) {
        B1[g] = pack_wfrag(W1, g, lane);
        B2[g] = pack_wfrag(W2, g, lane);
        T1[g] = Tl[g * 16 + (lane & 15)];
        F1[g] = Fl[g * 16 + (lane & 15)];
    }

    u64 st2[4] = {0, 0, 0, 0};
    const v4i zero = {0, 0, 0, 0};
    #pragma unroll
    for (int t = 0; t < 4; ++t) {
        const int tile = wg * 4 + t;
        const int tb = tile * 16;
        v4i a1 = A1f[(size_t)(tb + (lane & 15)) * 4 + (lane >> 4)];
        u32 vst = 0;
        #pragma unroll
        for (int g = 0; g < 4; ++g) {
            v4i d = mfma_i8(a1, B1[g], zero);
            #pragma unroll
            for (int r = 0; r < 4; ++r) {
                int dd = F1[g] ? -d[r] : d[r];
                u64 m = __ballot(dd >= T1[g]);
                vst = vst_select(vst, m, g * 4 + r, lane);
            }
        }
        if (lane < 32) A2B[(size_t)tile * 32 + lane] = vst;
        v4i a2 = frag_from_vst(vst, lut, lane);
        #pragma unroll
        for (int g = 0; g < 4; ++g) {
            v4i d2 = mfma_i8(a2, B2[g], zero);
            #pragma unroll
            for (int r = 0; r < 4; ++r) {
                int v = d2[r];
                st2[g] += ((u64)(u32)v << 32) | (u32)(v * v);
            }
        }
    }
    #pragma unroll
    for (int g = 0; g < 4; ++g) red[wib][g][lane] = st2[g];
    __syncthreads();
    if (threadIdx.x < 64) {
        const int g = threadIdx.x >> 4, c = threadIdx.x & 15;
        u64 tot = 0;
        #pragma unroll
        for (int w = 0; w < 4; ++w)
            #pragma unroll
            for (int lg = 0; lg < 4; ++lg) tot += red[w][g][c + 16 * lg];
        atomicAdd(&stats[(blockIdx.x & (NREP - 1)) * 256 + 64 + threadIdx.x], tot);
    }
}

// -- kD: A2 ballots -> D2 -> binarize -> A3 -> D3 -> stats3 + row max/min ----
__global__ void __launch_bounds__(256) kD(
    const u64* __restrict__ A2B64, const float* __restrict__ W2,
    const float* __restrict__ W3, const float* __restrict__ s2,
    const float* __restrict__ g2, const float* __restrict__ b2,
    short* __restrict__ dmm, u64* __restrict__ stats) {
    __shared__ u64 lut[256];
    __shared__ int Tl[64], Fl[64];
    __shared__ u64 red[4][8][64];
    build_lut(lut);
    if (threadIdx.x < 64) {
        float a, b;
        affine_from_stats(stats, 64 + threadIdx.x, s2, g2, b2, threadIdx.x, a, b);
        bool fl;
        Tl[threadIdx.x] = make_thresh(a, b, fl);
        Fl[threadIdx.x] = fl ? 1 : 0;
    }
    __syncthreads();

    const int lane = threadIdx.x & 63;
    const int wib = threadIdx.x >> 6;
    const int wg = (blockIdx.x << 2) | wib;        // 4096 waves; rows 2wg,2wg+1

    v4i B2f[4], B3[8];
    int T2[4], F2[4];
    #pragma unroll
    for (int g = 0; g < 4; ++g) {
        B2f[g] = pack_wfrag(W2, g, lane);
        T2[g] = Tl[g * 16 + (lane & 15)];
        F2[g] = Fl[g * 16 + (lane & 15)];
    }
    #pragma unroll
    for (int g = 0; g < 8; ++g) B3[g] = pack_wfrag(W3, g, lane);

    u64 st3[8] = {0, 0, 0, 0, 0, 0, 0, 0};
    const v4i zero = {0, 0, 0, 0};
    const int bsrc = ((lane >> 4) << 2) | (lane & 3);
    #pragma unroll
    for (int rr = 0; rr < 2; ++rr) {
        int mx[8], mn[8];
        #pragma unroll
        for (int g = 0; g < 8; ++g) { mx[g] = -127; mn[g] = 127; }
        #pragma unroll
        for (int tt = 0; tt < 2; ++tt) {
            const int tile = wg * 4 + rr * 2 + tt;
            u64 bits = A2B64[(size_t)tile * 16 + bsrc];
            v4i a2 = frag_from_bits(bits, lut, lane);
            u32 vst = 0;
            #pragma unroll
            for (int g = 0; g < 4; ++g) {
                v4i d2 = mfma_i8(a2, B2f[g], zero);
                #pragma unroll
                for (int r = 0; r < 4; ++r) {
                    int dd = F2[g] ? -d2[r] : d2[r];
                    u64 m = __ballot(dd >= T2[g]);
                    vst = vst_select(vst, m, g * 4 + r, lane);
                }
            }
            v4i a3 = frag_from_vst(vst, lut, lane);
            #pragma unroll
            for (int g = 0; g < 8; ++g) {
                v4i d3 = mfma_i8(a3, B3[g], zero);
                #pragma unroll
                for (int r = 0; r < 4; ++r) {
                    int v = d3[r];
                    st3[g] += ((u64)(u32)v << 32) | (u32)(v * v);
                    mx[g] = max(mx[g], v);
                    mn[g] = min(mn[g], v);
                }
            }
        }
        const int row = 2 * wg + rr;
        #pragma unroll
        for (int g = 0; g < 8; ++g) {
            int x = mx[g];
            x = max(x, __shfl_xor(x, 16));
            x = max(x, __shfl_xor(x, 32));
            int n = mn[g];
            n = min(n, __shfl_xor(n, 16));
            n = min(n, __shfl_xor(n, 32));
            if (lane < 16)
                dmm[row * 128 + g * 16 + lane] = (short)((x & 0xFF) | ((n & 0xFF) << 8));
        }
    }
    #pragma unroll
    for (int g = 0; g < 8; ++g) red[wib][g][lane] = st3[g];
    __syncthreads();
    if (threadIdx.x < 128) {
        const int g = threadIdx.x >> 4, c = threadIdx.x & 15;
        u64 tot = 0;
        #pragma unroll
        for (int w = 0; w < 4; ++w)
            #pragma unroll
            for (int lg = 0; lg < 4; ++lg) tot += red[w][g][c + 16 * lg];
        atomicAdd(&stats[(blockIdx.x & (NREP - 1)) * 256 + 128 + threadIdx.x], tot);
    }
}

// -------- kE: v = a*(a>=0?dmax:dmin)+b, ReLU, write [8192,128] --------------
__global__ void __launch_bounds__(512) kE(
    const short* __restrict__ dmm, const float* __restrict__ scale,
    const float* __restrict__ gamma, const float* __restrict__ beta,
    const u64* __restrict__ stats, float* __restrict__ out) {
    __shared__ float sa[128], sb[128];
    if (threadIdx.x < 128)
        affine_from_stats(stats, 128 + threadIdx.x, scale, gamma, beta,
                          threadIdx.x, sa[threadIdx.x], sb[threadIdx.x]);
    __syncthreads();
    const int idx = blockIdx.x * 512 + threadIdx.x;
    const int o = idx & 127;
    short pk = dmm[idx];
    int mx = (signed char)(pk & 0xFF);
    int mn = (signed char)((pk >> 8) & 0xFF);
    float a = sa[o], b = sb[o];
    float v = fmaf(a, (float)(a >= 0.f ? mx : mn), b);
    out[idx] = fmaxf(v, 0.f);
}

extern "C" void kernel_launch(void* const* d_in, const int* in_sizes, int n_in,
                              void* d_out, int out_size, void* d_ws, size_t ws_size,
                              hipStream_t stream) {
    const float* agg = (const float*)d_in[0];
    const float* W1 = (const float*)d_in[1];
    const float* s1 = (const float*)d_in[2];
    const float* g1 = (const float*)d_in[3];
    const float* b1 = (const float*)d_in[4];
    const float* W2 = (const float*)d_in[5];
    const float* s2 = (const float*)d_in[6];
    const float* g2 = (const float*)d_in[7];
    const float* b2 = (const float*)d_in[8];
    const float* W3 = (const float*)d_in[9];
    const float* s3 = (const float*)d_in[10];
    const float* g3 = (const float*)d_in[11];
    const float* b3 = (const float*)d_in[12];
    float* out = (float*)d_out;

    char* ws = (char*)d_ws;
    ulonglong2* wp1 = (ulonglong2*)(ws + 0);                 // 1 KB
    u64* stats = (u64*)(ws + 4096);                          // 32 KB
    u32* A1u = (u32*)(ws + 65536);                           // 16 MB sign-i8
    u32* A2B = (u32*)(ws + 65536 + (size_t)16 * 1024 * 1024);          // 2 MB ballots
    short* dmm = (short*)(ws + 65536 + (size_t)18 * 1024 * 1024);      // 2 MB

    k0_pack<<<1, 256, 0, stream>>>(W1, wp1, stats);
    kA<<<2048, 256, 0, stream>>>((const float4*)agg, wp1, A1u, stats);
    kC<<<1024, 256, 0, stream>>>((const v4i*)A1u, W1, W2, s1, g1, b1, A2B, stats);
    kD<<<1024, 256, 0, stream>>>((const u64*)A2B, W2, W3, s2, g2, b2, dmm, stats);
    kE<<<2048, 512, 0, stream>>>(dmm, s3, g3, b3, stats, out);
}